// Round 1
// baseline (130413.672 us; speedup 1.0000x reference)
//
#include <hip/hip_runtime.h>

// ---------------- problem constants ----------------
#define D_HH   1024
#define DR1    512
#define DR2    256
#define TSTEPS 8192
#define LAYERS 2

// ---------------- scan kernel config ----------------
#define NB    64          // persistent workgroups (all co-resident: 64 << 256 CUs)
#define BS    512         // threads per WG (8 waves)
#define HA    (D_HH / NB) // 16 h-rows owned per WG
#define QA    ((DR1 + DR2) / NB) // 12 reservoir rows per WG
#define NROWB (HA + QA)   // 28 phase-B row-dots per WG

__device__ __forceinline__ float dot4f(float4 a, float4 b) {
    return fmaf(a.x, b.x, fmaf(a.y, b.y, fmaf(a.z, b.z, a.w * b.w)));
}

// Persistent recurrent scan. Cross-WG data exchange uses 8-byte tagged atomic
// values: (tag << 32) | float_bits, agent scope. A consumer spins until the
// tag reaches its step target; value+tag arrive atomically so no fences or
// barrier flags are needed. Tag schedule:
//   h[i]  written in phase A of step t with tag t+1
//   r[j]  written in phase B of step t with tag t+1 (memset 0 => r_{-1}=0, tag 0)
__global__ __launch_bounds__(BS, 2) void crsd_scan(
    const float* __restrict__ pre,   // (T, D_HH): Wx @ x_t (bias NOT included)
    const float* __restrict__ Wh,    // (D_HH, D_HH) row-major
    const float* __restrict__ V1,    // (D_HH, DR1)
    const float* __restrict__ V2,    // (D_HH, DR2)
    const float* __restrict__ U1,    // (DR1, D_HH)
    const float* __restrict__ U2,    // (DR2, D_HH)
    const float* __restrict__ bias,  // (D_HH)
    float* __restrict__ out,         // (T, D_HH)
    unsigned long long* hstate,      // tagged h, D_HH entries (memset 0 before launch)
    unsigned long long* rstate)      // tagged r, DR1+DR2 entries (memset 0 before launch)
{
    const int g   = blockIdx.x;
    const int tid = threadIdx.x;

    __shared__ __align__(16) float r_s[DR1 + DR2];
    __shared__ __align__(16) float h_s[D_HH];
    __shared__ float zw[HA];   // z_w = pre[t] + b + Wh h_{t-1} for owned rows

    // ---- phase A role: row rA (32 lanes per row), V-weights in VGPRs ----
    const int rA = tid >> 5;        // 0..15
    const int p  = tid & 31;
    const int iA = g * HA + rA;     // global h-row
    float4 wa[6];
    {
        const float4* v1r = (const float4*)(V1 + (size_t)iA * DR1 + p * 16);
        wa[0] = v1r[0]; wa[1] = v1r[1]; wa[2] = v1r[2]; wa[3] = v1r[3];
        const float4* v2r = (const float4*)(V2 + (size_t)iA * DR2 + p * 8);
        wa[4] = v2r[0]; wa[5] = v2r[1];
    }

    // ---- phase B role: row rB (16 lanes per row), Wh/U-weights in VGPRs ----
    const int rB = tid >> 4;        // 0..31 (28 active)
    const int q  = tid & 15;
    const bool isZ = (rB < HA);                      // Wh rows -> z_w
    const bool isQ = (rB >= HA) && (rB < NROWB);     // U rows  -> reservoir
    int jG = 0;
    float bi = 0.f;
    const float* brow = Wh;  // safe dummy for inactive threads
    if (isZ) {
        brow = Wh + (size_t)(g * HA + rB) * D_HH;
        bi   = bias[g * HA + rB];
    } else if (isQ) {
        jG = g * QA + (rB - HA);
        brow = (jG < DR1) ? (U1 + (size_t)jG * D_HH)
                          : (U2 + (size_t)(jG - DR1) * D_HH);
    }
    float4 wb[16];
    {
        const float4* br = (const float4*)(brow + q * 64);
#pragma unroll
        for (int k = 0; k < 16; ++k) wb[k] = br[k];
    }

    float rloc = 0.f;   // owned reservoir element (isQ && q==0)

    // prologue: z_w for t=0 (h_{-1}=0 so no Wh term)
    if (isZ && q == 0) zw[rB] = pre[g * HA + rB] + bi;
    // (first iteration's post-r-stage __syncthreads orders this vs readers)

    for (int t = 0; t < TSTEPS; ++t) {
        // ---- stage r_{t-1}: poll tags >= t ----
        for (int idx = tid; idx < DR1 + DR2; idx += BS) {
            unsigned long long v;
            do {
                v = __hip_atomic_load(&rstate[idx], __ATOMIC_RELAXED,
                                      __HIP_MEMORY_SCOPE_AGENT);
            } while ((int)(v >> 32) < t);
            r_s[idx] = __uint_as_float((unsigned)v);
        }
        __syncthreads();

        // ---- phase A: h_t = tanh(zw + V1 r1 + V2 r2) ----
        {
            const float4* r1v = (const float4*)r_s + p * 4;
            const float4* r2v = (const float4*)(r_s + DR1) + p * 2;
            float acc = dot4f(wa[0], r1v[0]);
            acc += dot4f(wa[1], r1v[1]);
            acc += dot4f(wa[2], r1v[2]);
            acc += dot4f(wa[3], r1v[3]);
            acc += dot4f(wa[4], r2v[0]);
            acc += dot4f(wa[5], r2v[1]);
#pragma unroll
            for (int m = 16; m >= 1; m >>= 1) acc += __shfl_xor(acc, m);
            if (p == 0) {
                float hv = tanhf(zw[rA] + acc);
                out[(size_t)t * D_HH + iA] = hv;
                unsigned long long pv =
                    ((unsigned long long)(unsigned)(t + 1) << 32) | __float_as_uint(hv);
                __hip_atomic_store(&hstate[iA], pv, __ATOMIC_RELAXED,
                                   __HIP_MEMORY_SCOPE_AGENT);
            }
        }

        // prefetch pre[t+1] (independent of the h broadcast; hides L3/HBM latency)
        float preN = 0.f;
        if (isZ && q == 0 && t + 1 < TSTEPS)
            preN = pre[(size_t)(t + 1) * D_HH + g * HA + rB];

        // ---- stage h_t: poll tags >= t+1 ----
        for (int idx = tid; idx < D_HH; idx += BS) {
            unsigned long long v;
            do {
                v = __hip_atomic_load(&hstate[idx], __ATOMIC_RELAXED,
                                      __HIP_MEMORY_SCOPE_AGENT);
            } while ((int)(v >> 32) < t + 1);
            h_s[idx] = __uint_as_float((unsigned)v);
        }
        __syncthreads();

        // ---- phase B: q-rows = U h_t (reservoir update), z-rows = Wh h_t (+pre+b) ----
        {
            const float4* hv4 = (const float4*)h_s + q * 16;
            float acc = 0.f;
#pragma unroll
            for (int k = 0; k < 16; ++k) acc += dot4f(wb[k], hv4[k]);
#pragma unroll
            for (int m = 8; m >= 1; m >>= 1) acc += __shfl_xor(acc, m);
            if (q == 0) {
                if (isZ) {
                    zw[rB] = bi + acc + preN;
                } else if (isQ) {
                    rloc = 0.9f * rloc + 0.1f * tanhf(acc);
                    unsigned long long pv =
                        ((unsigned long long)(unsigned)(t + 1) << 32) | __float_as_uint(rloc);
                    __hip_atomic_store(&rstate[jG], pv, __ATOMIC_RELAXED,
                                       __HIP_MEMORY_SCOPE_AGENT);
                }
            }
        }
    }
}

// ---------------- pre = X @ W^T  (NT f32 GEMM, 128x128 tile, 8x8/thread) ----
#define GBM 128
#define GBN 128
#define GBK 16

__global__ __launch_bounds__(256) void gemm_nt_kernel(
    const float* __restrict__ A,  // (M, K) row-major
    const float* __restrict__ B,  // (N, K) row-major  (i.e. C = A @ B^T)
    float* __restrict__ C)        // (M, N=D_HH)
{
    __shared__ float As[GBK][GBM];  // k-major
    __shared__ float Bs[GBK][GBN];
    const int K   = D_HH;
    const int tid = threadIdx.x;
    const int tx  = tid & 15, ty = tid >> 4;
    const int m0  = blockIdx.x * GBM, n0 = blockIdx.y * GBN;
    const int lrow = tid >> 1, lk = (tid & 1) * 8;

    float acc[8][8];
#pragma unroll
    for (int i = 0; i < 8; ++i)
#pragma unroll
        for (int j = 0; j < 8; ++j) acc[i][j] = 0.f;

    for (int k0 = 0; k0 < K; k0 += GBK) {
        const float4 a0 = *(const float4*)&A[(size_t)(m0 + lrow) * K + k0 + lk];
        const float4 a1 = *(const float4*)&A[(size_t)(m0 + lrow) * K + k0 + lk + 4];
        const float4 b0 = *(const float4*)&B[(size_t)(n0 + lrow) * K + k0 + lk];
        const float4 b1 = *(const float4*)&B[(size_t)(n0 + lrow) * K + k0 + lk + 4];
        __syncthreads();   // previous iteration's LDS reads complete
        As[lk + 0][lrow] = a0.x; As[lk + 1][lrow] = a0.y;
        As[lk + 2][lrow] = a0.z; As[lk + 3][lrow] = a0.w;
        As[lk + 4][lrow] = a1.x; As[lk + 5][lrow] = a1.y;
        As[lk + 6][lrow] = a1.z; As[lk + 7][lrow] = a1.w;
        Bs[lk + 0][lrow] = b0.x; Bs[lk + 1][lrow] = b0.y;
        Bs[lk + 2][lrow] = b0.z; Bs[lk + 3][lrow] = b0.w;
        Bs[lk + 4][lrow] = b1.x; Bs[lk + 5][lrow] = b1.y;
        Bs[lk + 6][lrow] = b1.z; Bs[lk + 7][lrow] = b1.w;
        __syncthreads();
#pragma unroll
        for (int k = 0; k < GBK; ++k) {
            const float4 xa0 = *(const float4*)&As[k][ty * 8];
            const float4 xa1 = *(const float4*)&As[k][ty * 8 + 4];
            const float4 wb0 = *(const float4*)&Bs[k][tx * 8];
            const float4 wb1 = *(const float4*)&Bs[k][tx * 8 + 4];
            const float xa[8] = {xa0.x, xa0.y, xa0.z, xa0.w, xa1.x, xa1.y, xa1.z, xa1.w};
            const float wv[8] = {wb0.x, wb0.y, wb0.z, wb0.w, wb1.x, wb1.y, wb1.z, wb1.w};
#pragma unroll
            for (int i = 0; i < 8; ++i)
#pragma unroll
                for (int j = 0; j < 8; ++j)
                    acc[i][j] = fmaf(xa[i], wv[j], acc[i][j]);
        }
    }

    const int orow = m0 + ty * 8;
    const int ocol = n0 + tx * 8;
#pragma unroll
    for (int i = 0; i < 8; ++i) {
        float4 o0 = make_float4(acc[i][0], acc[i][1], acc[i][2], acc[i][3]);
        float4 o1 = make_float4(acc[i][4], acc[i][5], acc[i][6], acc[i][7]);
        *(float4*)&C[(size_t)(orow + i) * D_HH + ocol]     = o0;
        *(float4*)&C[(size_t)(orow + i) * D_HH + ocol + 4] = o1;
    }
}

extern "C" void kernel_launch(void* const* d_in, const int* in_sizes, int n_in,
                              void* d_out, int out_size, void* d_ws, size_t ws_size,
                              hipStream_t stream)
{
    const float* x  = (const float*)d_in[0];   // (T, D_HH)
    const float* Wx = (const float*)d_in[1];   // (L, D_HH, D_HH)
    const float* Wh = (const float*)d_in[2];   // (L, D_HH, D_HH)
    const float* b  = (const float*)d_in[3];   // (L, D_HH)
    const float* V1 = (const float*)d_in[4];   // (L, D_HH, DR1)
    const float* U1 = (const float*)d_in[5];   // (L, DR1, D_HH)
    const float* V2 = (const float*)d_in[6];   // (L, D_HH, DR2)
    const float* U2 = (const float*)d_in[7];   // (L, DR2, D_HH)
    float* out = (float*)d_out;                // (T, D_HH)

    char* ws = (char*)d_ws;
    float* pre = (float*)ws;                                   // T*D_HH f32 (32 MB)
    const size_t preB = (size_t)TSTEPS * D_HH * sizeof(float);
    unsigned long long* hstate = (unsigned long long*)(ws + preB);     // 1024 * 8B
    unsigned long long* rstate = hstate + D_HH;                        // 768  * 8B
    const size_t stateB = (size_t)(D_HH + DR1 + DR2) * sizeof(unsigned long long);

    const dim3 ggrid(TSTEPS / GBM, D_HH / GBN);

    for (int l = 0; l < LAYERS; ++l) {
        const float* xin = (l == 0) ? x : out;   // layer 2 input = layer 1 output seq
        // reset tagged state (tags->0, values->0.0f == initial h/r state)
        hipMemsetAsync(hstate, 0, stateB, stream);
        // pre = xin @ Wx[l]^T
        gemm_nt_kernel<<<ggrid, 256, 0, stream>>>(
            xin, Wx + (size_t)l * D_HH * D_HH, pre);
        // persistent sequential scan
        crsd_scan<<<dim3(NB), dim3(BS), 0, stream>>>(
            pre,
            Wh + (size_t)l * D_HH * D_HH,
            V1 + (size_t)l * D_HH * DR1,
            V2 + (size_t)l * D_HH * DR2,
            U1 + (size_t)l * DR1 * D_HH,
            U2 + (size_t)l * DR2 * D_HH,
            b  + (size_t)l * D_HH,
            out, hstate, rstate);
    }
}

// Round 2
// 71962.006 us; speedup vs baseline: 1.8123x; 1.8123x over previous
//
#include <hip/hip_runtime.h>

// ---------------- problem constants ----------------
#define D_HH   1024
#define DR1    512
#define DR2    256
#define TSTEPS 8192
#define LAYERS 2

// ---------------- scan kernel config ----------------
#define NB    64          // persistent workgroups
#define BS    512         // threads per WG (8 waves)
#define HA    (D_HH / NB) // 16 h-rows owned per WG
#define QA    ((DR1 + DR2) / NB) // 12 reservoir rows per WG
#define NROWB (HA + QA)   // 28 phase-B row-dots per WG

__device__ __forceinline__ float dot4f(float4 a, float4 b) {
    return fmaf(a.x, b.x, fmaf(a.y, b.y, fmaf(a.z, b.z, a.w * b.w)));
}

// Persistent recurrent scan. Cross-WG exchange = 8-byte tagged atomic values
// (tag<<32)|float_bits at agent scope; consumers spin on the data itself.
//   h[i] written in phase A of step t with tag t+1
//   r[j] written in phase B of step t with tag t+1 (memset 0 => r_{-1}=0, tag 0)
//
// LDS access pattern: lane-linear 16B chunks (lane p owns bytes p*16 + 512k of
// r, q*16 + 256k of h) so every 8-lane service group covers all 32 banks.
// Weight registers are loaded in the SAME permuted order, so dots stay correct.
__global__ __launch_bounds__(BS, 2) void crsd_scan(
    const float* __restrict__ pre,   // (T, D_HH): Wx @ x_t (bias NOT included)
    const float* __restrict__ Wh,    // (D_HH, D_HH) row-major
    const float* __restrict__ V1,    // (D_HH, DR1)
    const float* __restrict__ V2,    // (D_HH, DR2)
    const float* __restrict__ U1,    // (DR1, D_HH)
    const float* __restrict__ U2,    // (DR2, D_HH)
    const float* __restrict__ bias,  // (D_HH)
    float* __restrict__ out,         // (T, D_HH)
    unsigned long long* hstate,      // tagged h, D_HH entries (memset 0)
    unsigned long long* rstate)      // tagged r, DR1+DR2 entries (memset 0)
{
    const int g   = blockIdx.x;
    const int tid = threadIdx.x;

    __shared__ __align__(16) float r_s[DR1 + DR2];
    __shared__ __align__(16) float h_s[D_HH];
    __shared__ float zw[HA];   // z_w = pre[t] + b + Wh h_{t-1} for owned rows

    // ---- phase A role: row rA (32 lanes per row), V-weights in VGPRs ----
    // lane p owns float4 chunks {p + 32k} of r1 (k=0..3) and of r2 (k=0..1)
    const int rA = tid >> 5;        // 0..15
    const int p  = tid & 31;
    const int iA = g * HA + rA;     // global h-row
    float4 wa[6];
    {
        const float4* v1r = (const float4*)(V1 + (size_t)iA * DR1);
#pragma unroll
        for (int k = 0; k < 4; ++k) wa[k] = v1r[p + 32 * k];
        const float4* v2r = (const float4*)(V2 + (size_t)iA * DR2);
#pragma unroll
        for (int k = 0; k < 2; ++k) wa[4 + k] = v2r[p + 32 * k];
    }

    // ---- phase B role: row rB (16 lanes per row), Wh/U-weights in VGPRs ----
    // lane q owns float4 chunks {q + 16k} of h (k=0..15)
    const int rB = tid >> 4;        // 0..31 (28 active; wave 7 idle)
    const int q  = tid & 15;
    const bool isZ = (rB < HA);                      // Wh rows -> z_w
    const bool isQ = (rB >= HA) && (rB < NROWB);     // U rows  -> reservoir
    int jG = 0;
    float bi = 0.f;
    const float* brow = Wh;  // safe dummy for inactive threads
    if (isZ) {
        brow = Wh + (size_t)(g * HA + rB) * D_HH;
        bi   = bias[g * HA + rB];
    } else if (isQ) {
        jG = g * QA + (rB - HA);
        brow = (jG < DR1) ? (U1 + (size_t)jG * D_HH)
                          : (U2 + (size_t)(jG - DR1) * D_HH);
    }
    float4 wb[16];
    {
        const float4* br = (const float4*)brow;
#pragma unroll
        for (int k = 0; k < 16; ++k) wb[k] = br[q + 16 * k];
    }

    float rloc = 0.f;   // owned reservoir element (isQ && q==0)

    // prologue: z_w for t=0 (h_{-1}=0 so no Wh term)
    if (isZ && q == 0) zw[rB] = pre[g * HA + rB] + bi;
    // (first iteration's post-r-stage __syncthreads orders this vs readers)

    for (int t = 0; t < TSTEPS; ++t) {
        // ---- stage r_{t-1}: dual-outstanding poll, tags >= t ----
        {
            const bool has1 = (tid < (DR1 + DR2 - BS));   // tid < 256
            bool d0 = false, d1 = !has1;
            while (true) {
                unsigned long long v0 = 0, v1 = 0;
                if (!d0) v0 = __hip_atomic_load(&rstate[tid], __ATOMIC_RELAXED,
                                                __HIP_MEMORY_SCOPE_AGENT);
                if (!d1) v1 = __hip_atomic_load(&rstate[tid + BS], __ATOMIC_RELAXED,
                                                __HIP_MEMORY_SCOPE_AGENT);
                if (!d0 && (int)(v0 >> 32) >= t) {
                    r_s[tid] = __uint_as_float((unsigned)v0); d0 = true;
                }
                if (!d1 && (int)(v1 >> 32) >= t) {
                    r_s[tid + BS] = __uint_as_float((unsigned)v1); d1 = true;
                }
                if (d0 && d1) break;
                __builtin_amdgcn_s_sleep(1);
            }
        }
        __syncthreads();

        // ---- phase A: h_t = tanh(zw + V1 r1 + V2 r2) ----
        {
            const float4* r1v = (const float4*)r_s;
            const float4* r2v = (const float4*)(r_s + DR1);
            float acc = dot4f(wa[0], r1v[p]);
            acc += dot4f(wa[1], r1v[p + 32]);
            acc += dot4f(wa[2], r1v[p + 64]);
            acc += dot4f(wa[3], r1v[p + 96]);
            acc += dot4f(wa[4], r2v[p]);
            acc += dot4f(wa[5], r2v[p + 32]);
#pragma unroll
            for (int m = 16; m >= 1; m >>= 1) acc += __shfl_xor(acc, m);
            if (p == 0) {
                float hv = tanhf(zw[rA] + acc);
                out[(size_t)t * D_HH + iA] = hv;
                unsigned long long pv =
                    ((unsigned long long)(unsigned)(t + 1) << 32) | __float_as_uint(hv);
                __hip_atomic_store(&hstate[iA], pv, __ATOMIC_RELAXED,
                                   __HIP_MEMORY_SCOPE_AGENT);
            }
        }

        // prefetch pre[t+1] (independent of the h broadcast)
        float preN = 0.f;
        if (isZ && q == 0 && t + 1 < TSTEPS)
            preN = pre[(size_t)(t + 1) * D_HH + g * HA + rB];

        // ---- stage h_t: dual-outstanding poll, tags >= t+1 ----
        {
            bool d0 = false, d1 = false;
            while (true) {
                unsigned long long v0 = 0, v1 = 0;
                if (!d0) v0 = __hip_atomic_load(&hstate[tid], __ATOMIC_RELAXED,
                                                __HIP_MEMORY_SCOPE_AGENT);
                if (!d1) v1 = __hip_atomic_load(&hstate[tid + BS], __ATOMIC_RELAXED,
                                                __HIP_MEMORY_SCOPE_AGENT);
                if (!d0 && (int)(v0 >> 32) >= t + 1) {
                    h_s[tid] = __uint_as_float((unsigned)v0); d0 = true;
                }
                if (!d1 && (int)(v1 >> 32) >= t + 1) {
                    h_s[tid + BS] = __uint_as_float((unsigned)v1); d1 = true;
                }
                if (d0 && d1) break;
                __builtin_amdgcn_s_sleep(1);
            }
        }
        __syncthreads();

        // ---- phase B: q-rows = U h_t (reservoir), z-rows = Wh h_t (+pre+b) ----
        if (rB < NROWB) {
            const float4* hv4 = (const float4*)h_s;
            float acc = 0.f;
#pragma unroll
            for (int k = 0; k < 16; ++k) acc += dot4f(wb[k], hv4[q + 16 * k]);
#pragma unroll
            for (int m = 8; m >= 1; m >>= 1) acc += __shfl_xor(acc, m);
            if (q == 0) {
                if (isZ) {
                    zw[rB] = bi + acc + preN;
                } else {
                    rloc = 0.9f * rloc + 0.1f * tanhf(acc);
                    unsigned long long pv =
                        ((unsigned long long)(unsigned)(t + 1) << 32) | __float_as_uint(rloc);
                    __hip_atomic_store(&rstate[jG], pv, __ATOMIC_RELAXED,
                                       __HIP_MEMORY_SCOPE_AGENT);
                }
            }
        }
    }
}

// ---------------- pre = X @ W^T  (NT f32 GEMM, 128x128 tile, 8x8/thread) ----
#define GBM 128
#define GBN 128
#define GBK 16

__global__ __launch_bounds__(256) void gemm_nt_kernel(
    const float* __restrict__ A,  // (M, K) row-major
    const float* __restrict__ B,  // (N, K) row-major  (i.e. C = A @ B^T)
    float* __restrict__ C)        // (M, N=D_HH)
{
    __shared__ float As[GBK][GBM];  // k-major
    __shared__ float Bs[GBK][GBN];
    const int K   = D_HH;
    const int tid = threadIdx.x;
    const int tx  = tid & 15, ty = tid >> 4;
    const int m0  = blockIdx.x * GBM, n0 = blockIdx.y * GBN;
    const int lrow = tid >> 1, lk = (tid & 1) * 8;

    float acc[8][8];
#pragma unroll
    for (int i = 0; i < 8; ++i)
#pragma unroll
        for (int j = 0; j < 8; ++j) acc[i][j] = 0.f;

    for (int k0 = 0; k0 < K; k0 += GBK) {
        const float4 a0 = *(const float4*)&A[(size_t)(m0 + lrow) * K + k0 + lk];
        const float4 a1 = *(const float4*)&A[(size_t)(m0 + lrow) * K + k0 + lk + 4];
        const float4 b0 = *(const float4*)&B[(size_t)(n0 + lrow) * K + k0 + lk];
        const float4 b1 = *(const float4*)&B[(size_t)(n0 + lrow) * K + k0 + lk + 4];
        __syncthreads();   // previous iteration's LDS reads complete
        As[lk + 0][lrow] = a0.x; As[lk + 1][lrow] = a0.y;
        As[lk + 2][lrow] = a0.z; As[lk + 3][lrow] = a0.w;
        As[lk + 4][lrow] = a1.x; As[lk + 5][lrow] = a1.y;
        As[lk + 6][lrow] = a1.z; As[lk + 7][lrow] = a1.w;
        Bs[lk + 0][lrow] = b0.x; Bs[lk + 1][lrow] = b0.y;
        Bs[lk + 2][lrow] = b0.z; Bs[lk + 3][lrow] = b0.w;
        Bs[lk + 4][lrow] = b1.x; Bs[lk + 5][lrow] = b1.y;
        Bs[lk + 6][lrow] = b1.z; Bs[lk + 7][lrow] = b1.w;
        __syncthreads();
#pragma unroll
        for (int k = 0; k < GBK; ++k) {
            const float4 xa0 = *(const float4*)&As[k][ty * 8];
            const float4 xa1 = *(const float4*)&As[k][ty * 8 + 4];
            const float4 wb0 = *(const float4*)&Bs[k][tx * 8];
            const float4 wb1 = *(const float4*)&Bs[k][tx * 8 + 4];
            const float xa[8] = {xa0.x, xa0.y, xa0.z, xa0.w, xa1.x, xa1.y, xa1.z, xa1.w};
            const float wv[8] = {wb0.x, wb0.y, wb0.z, wb0.w, wb1.x, wb1.y, wb1.z, wb1.w};
#pragma unroll
            for (int i = 0; i < 8; ++i)
#pragma unroll
                for (int j = 0; j < 8; ++j)
                    acc[i][j] = fmaf(xa[i], wv[j], acc[i][j]);
        }
    }

    const int orow = m0 + ty * 8;
    const int ocol = n0 + tx * 8;
#pragma unroll
    for (int i = 0; i < 8; ++i) {
        float4 o0 = make_float4(acc[i][0], acc[i][1], acc[i][2], acc[i][3]);
        float4 o1 = make_float4(acc[i][4], acc[i][5], acc[i][6], acc[i][7]);
        *(float4*)&C[(size_t)(orow + i) * D_HH + ocol]     = o0;
        *(float4*)&C[(size_t)(orow + i) * D_HH + ocol + 4] = o1;
    }
}

extern "C" void kernel_launch(void* const* d_in, const int* in_sizes, int n_in,
                              void* d_out, int out_size, void* d_ws, size_t ws_size,
                              hipStream_t stream)
{
    const float* x  = (const float*)d_in[0];   // (T, D_HH)
    const float* Wx = (const float*)d_in[1];   // (L, D_HH, D_HH)
    const float* Wh = (const float*)d_in[2];   // (L, D_HH, D_HH)
    const float* b  = (const float*)d_in[3];   // (L, D_HH)
    const float* V1 = (const float*)d_in[4];   // (L, D_HH, DR1)
    const float* U1 = (const float*)d_in[5];   // (L, DR1, D_HH)
    const float* V2 = (const float*)d_in[6];   // (L, D_HH, DR2)
    const float* U2 = (const float*)d_in[7];   // (L, DR2, D_HH)
    float* out = (float*)d_out;                // (T, D_HH)

    char* ws = (char*)d_ws;
    float* pre = (float*)ws;                                   // T*D_HH f32 (32 MB)
    const size_t preB = (size_t)TSTEPS * D_HH * sizeof(float);
    unsigned long long* hstate = (unsigned long long*)(ws + preB);     // 1024 * 8B
    unsigned long long* rstate = hstate + D_HH;                        // 768  * 8B
    const size_t stateB = (size_t)(D_HH + DR1 + DR2) * sizeof(unsigned long long);

    const dim3 ggrid(TSTEPS / GBM, D_HH / GBN);

    for (int l = 0; l < LAYERS; ++l) {
        const float* xin = (l == 0) ? x : out;   // layer 2 input = layer 1 output
        hipMemsetAsync(hstate, 0, stateB, stream);
        gemm_nt_kernel<<<ggrid, 256, 0, stream>>>(
            xin, Wx + (size_t)l * D_HH * D_HH, pre);
        crsd_scan<<<dim3(NB), dim3(BS), 0, stream>>>(
            pre,
            Wh + (size_t)l * D_HH * D_HH,
            V1 + (size_t)l * D_HH * DR1,
            V2 + (size_t)l * D_HH * DR2,
            U1 + (size_t)l * DR1 * D_HH,
            U2 + (size_t)l * DR2 * D_HH,
            b  + (size_t)l * D_HH,
            out, hstate, rstate);
    }
}

// Round 3
// 69913.593 us; speedup vs baseline: 1.8654x; 1.0293x over previous
//
#include <hip/hip_runtime.h>

// ---------------- problem constants ----------------
#define D_HH   1024
#define DR1    512
#define DR2    256
#define TSTEPS 8192
#define LAYERS 2

// ---------------- scan kernel config ----------------
#define NB    64          // persistent workgroups
#define BS    512         // threads per WG (8 waves)
#define HA    (D_HH / NB) // 16 h-rows owned per WG
#define QA    ((DR1 + DR2) / NB) // 12 reservoir rows per WG
#define NROWB (HA + QA)   // 28 phase-B row-dots per WG

#define HLINES (D_HH / 8)          // 128 tagged-entry cache lines of h
#define RLINES ((DR1 + DR2) / 8)   // 96 lines of r

typedef __attribute__((ext_vector_type(2))) unsigned long long ull2v;

__device__ __forceinline__ float dot4f(float4 a, float4 b) {
    return fmaf(a.x, b.x, fmaf(a.y, b.y, fmaf(a.z, b.z, a.w * b.w)));
}

// Poll one 64B line of tagged values ((tag<<32)|f32bits) until all 8 tags
// reach `target`; then stage the 8 values into LDS. sc1 loads bypass L2 so we
// always observe L3. waitcnt lives INSIDE the asm so the tag check can't be
// hoisted above load completion.
__device__ __forceinline__ void poll_line(const unsigned long long* base,
                                          int line, int target, float* ls) {
    const unsigned long long* p = base + 8 * (size_t)line;
    ull2v q0, q1, q2, q3;
    for (;;) {
        asm volatile(
            "global_load_dwordx4 %0, %4, off sc1\n\t"
            "global_load_dwordx4 %1, %4, off offset:16 sc1\n\t"
            "global_load_dwordx4 %2, %4, off offset:32 sc1\n\t"
            "global_load_dwordx4 %3, %4, off offset:48 sc1\n\t"
            "s_waitcnt vmcnt(0)"
            : "=&v"(q0), "=&v"(q1), "=&v"(q2), "=&v"(q3)
            : "v"(p)
            : "memory");
        int mn = (int)(q0[0] >> 32);
        mn = min(mn, (int)(q0[1] >> 32));
        mn = min(mn, (int)(q1[0] >> 32));
        mn = min(mn, (int)(q1[1] >> 32));
        mn = min(mn, (int)(q2[0] >> 32));
        mn = min(mn, (int)(q2[1] >> 32));
        mn = min(mn, (int)(q3[0] >> 32));
        mn = min(mn, (int)(q3[1] >> 32));
        if (mn >= target) break;
        __builtin_amdgcn_s_sleep(1);
    }
    float4 f0 = make_float4(__uint_as_float((unsigned)q0[0]),
                            __uint_as_float((unsigned)q0[1]),
                            __uint_as_float((unsigned)q1[0]),
                            __uint_as_float((unsigned)q1[1]));
    float4 f1 = make_float4(__uint_as_float((unsigned)q2[0]),
                            __uint_as_float((unsigned)q2[1]),
                            __uint_as_float((unsigned)q3[0]),
                            __uint_as_float((unsigned)q3[1]));
    *(float4*)&ls[8 * line]     = f0;
    *(float4*)&ls[8 * line + 4] = f1;
}

// Persistent recurrent scan. Cross-WG exchange = 8-byte tagged atomic values
// (tag<<32)|float_bits at agent scope; consumers spin on the data itself.
//   h[i] written in phase A of step t with tag t+1
//   r[j] written in phase B of step t with tag t+1 (memset 0 => r_{-1}=0, tag 0)
__global__ __launch_bounds__(BS, 2) void crsd_scan(
    const float* __restrict__ pre,   // (T, D_HH): Wx @ x_t (bias NOT included)
    const float* __restrict__ Wh,    // (D_HH, D_HH) row-major
    const float* __restrict__ V1,    // (D_HH, DR1)
    const float* __restrict__ V2,    // (D_HH, DR2)
    const float* __restrict__ U1,    // (DR1, D_HH)
    const float* __restrict__ U2,    // (DR2, D_HH)
    const float* __restrict__ bias,  // (D_HH)
    float* __restrict__ out,         // (T, D_HH)
    unsigned long long* hstate,      // tagged h, D_HH entries (memset 0)
    unsigned long long* rstate)      // tagged r, DR1+DR2 entries (memset 0)
{
    const int g   = blockIdx.x;
    const int tid = threadIdx.x;

    __shared__ __align__(16) float r_s[DR1 + DR2];
    __shared__ __align__(16) float h_s[D_HH];
    __shared__ float zw[HA];   // z_w = pre[t] + b + Wh h_{t-1} for owned rows

    // ---- phase A role: row rA (32 lanes per row), V-weights in VGPRs ----
    // lane p owns float4 chunks {p + 32k} of r1 (k=0..3) and of r2 (k=0..1)
    const int rA = tid >> 5;        // 0..15
    const int p  = tid & 31;
    const int iA = g * HA + rA;     // global h-row
    float4 wa[6];
    {
        const float4* v1r = (const float4*)(V1 + (size_t)iA * DR1);
#pragma unroll
        for (int k = 0; k < 4; ++k) wa[k] = v1r[p + 32 * k];
        const float4* v2r = (const float4*)(V2 + (size_t)iA * DR2);
#pragma unroll
        for (int k = 0; k < 2; ++k) wa[4 + k] = v2r[p + 32 * k];
    }

    // ---- phase B role: row rB (16 lanes per row), Wh/U-weights in VGPRs ----
    // lane q owns float4 chunks {q + 16k} of h (k=0..15)
    const int rB = tid >> 4;        // 0..31 (28 active; wave 7 idle)
    const int q  = tid & 15;
    const bool isZ = (rB < HA);                      // Wh rows -> z_w
    const bool isQ = (rB >= HA) && (rB < NROWB);     // U rows  -> reservoir
    int jG = 0;
    float bi = 0.f;
    const float* brow = Wh;  // safe dummy for inactive threads
    if (isZ) {
        brow = Wh + (size_t)(g * HA + rB) * D_HH;
        bi   = bias[g * HA + rB];
    } else if (isQ) {
        jG = g * QA + (rB - HA);
        brow = (jG < DR1) ? (U1 + (size_t)jG * D_HH)
                          : (U2 + (size_t)(jG - DR1) * D_HH);
    }
    float4 wb[16];
    {
        const float4* br = (const float4*)brow;
#pragma unroll
        for (int k = 0; k < 16; ++k) wb[k] = br[q + 16 * k];
    }

    float rloc = 0.f;   // owned reservoir element (isQ && q==0)

    // prologue: z_w for t=0 (h_{-1}=0 so no Wh term)
    if (isZ && q == 0) zw[rB] = pre[g * HA + rB] + bi;
    // (first iteration's post-r-stage __syncthreads orders this vs readers)

    for (int t = 0; t < TSTEPS; ++t) {
        // ---- stage r_{t-1}: one poller per 64B line, tags >= t ----
        if (tid < RLINES) poll_line(rstate, tid, t, r_s);
        __syncthreads();

        // ---- phase A: h_t = tanh(zw + V1 r1 + V2 r2) ----
        {
            const float4* r1v = (const float4*)r_s;
            const float4* r2v = (const float4*)(r_s + DR1);
            float acc = dot4f(wa[0], r1v[p]);
            acc += dot4f(wa[1], r1v[p + 32]);
            acc += dot4f(wa[2], r1v[p + 64]);
            acc += dot4f(wa[3], r1v[p + 96]);
            acc += dot4f(wa[4], r2v[p]);
            acc += dot4f(wa[5], r2v[p + 32]);
#pragma unroll
            for (int m = 16; m >= 1; m >>= 1) acc += __shfl_xor(acc, m);
            if (p == 0) {
                float hv = tanhf(zw[rA] + acc);
                // visibility first: tagged store, then LDS self-stage, then out
                unsigned long long pv =
                    ((unsigned long long)(unsigned)(t + 1) << 32) | __float_as_uint(hv);
                __hip_atomic_store(&hstate[iA], pv, __ATOMIC_RELAXED,
                                   __HIP_MEMORY_SCOPE_AGENT);
                h_s[iA] = hv;   // own lines are skipped by the h-poll below
                out[(size_t)t * D_HH + iA] = hv;
            }
        }

        // prefetch pre[t+1] (independent of the h broadcast)
        float preN = 0.f;
        if (isZ && q == 0 && t + 1 < TSTEPS)
            preN = pre[(size_t)(t + 1) * D_HH + g * HA + rB];

        // ---- stage h_t: one poller per line, skip own WG's 2 lines ----
        if (tid < HLINES && (tid >> 1) != g) poll_line(hstate, tid, t + 1, h_s);
        __syncthreads();

        // ---- phase B: q-rows = U h_t (reservoir), z-rows = Wh h_t (+pre+b) ----
        if (rB < NROWB) {
            const float4* hv4 = (const float4*)h_s;
            float acc = 0.f;
#pragma unroll
            for (int k = 0; k < 16; ++k) acc += dot4f(wb[k], hv4[q + 16 * k]);
#pragma unroll
            for (int m = 8; m >= 1; m >>= 1) acc += __shfl_xor(acc, m);
            if (q == 0) {
                if (isZ) {
                    zw[rB] = bi + acc + preN;
                } else {
                    rloc = 0.9f * rloc + 0.1f * tanhf(acc);
                    unsigned long long pv =
                        ((unsigned long long)(unsigned)(t + 1) << 32) | __float_as_uint(rloc);
                    __hip_atomic_store(&rstate[jG], pv, __ATOMIC_RELAXED,
                                       __HIP_MEMORY_SCOPE_AGENT);
                }
            }
        }
    }
}

// ---------------- pre = X @ W^T  (NT f32 GEMM, 128x128 tile, 8x8/thread) ----
#define GBM 128
#define GBN 128
#define GBK 16

__global__ __launch_bounds__(256) void gemm_nt_kernel(
    const float* __restrict__ A,  // (M, K) row-major
    const float* __restrict__ B,  // (N, K) row-major  (i.e. C = A @ B^T)
    float* __restrict__ C)        // (M, N=D_HH)
{
    __shared__ float As[GBK][GBM];  // k-major
    __shared__ float Bs[GBK][GBN];
    const int K   = D_HH;
    const int tid = threadIdx.x;
    const int tx  = tid & 15, ty = tid >> 4;
    const int m0  = blockIdx.x * GBM, n0 = blockIdx.y * GBN;
    const int lrow = tid >> 1, lk = (tid & 1) * 8;

    float acc[8][8];
#pragma unroll
    for (int i = 0; i < 8; ++i)
#pragma unroll
        for (int j = 0; j < 8; ++j) acc[i][j] = 0.f;

    for (int k0 = 0; k0 < K; k0 += GBK) {
        const float4 a0 = *(const float4*)&A[(size_t)(m0 + lrow) * K + k0 + lk];
        const float4 a1 = *(const float4*)&A[(size_t)(m0 + lrow) * K + k0 + lk + 4];
        const float4 b0 = *(const float4*)&B[(size_t)(n0 + lrow) * K + k0 + lk];
        const float4 b1 = *(const float4*)&B[(size_t)(n0 + lrow) * K + k0 + lk + 4];
        __syncthreads();   // previous iteration's LDS reads complete
        As[lk + 0][lrow] = a0.x; As[lk + 1][lrow] = a0.y;
        As[lk + 2][lrow] = a0.z; As[lk + 3][lrow] = a0.w;
        As[lk + 4][lrow] = a1.x; As[lk + 5][lrow] = a1.y;
        As[lk + 6][lrow] = a1.z; As[lk + 7][lrow] = a1.w;
        Bs[lk + 0][lrow] = b0.x; Bs[lk + 1][lrow] = b0.y;
        Bs[lk + 2][lrow] = b0.z; Bs[lk + 3][lrow] = b0.w;
        Bs[lk + 4][lrow] = b1.x; Bs[lk + 5][lrow] = b1.y;
        Bs[lk + 6][lrow] = b1.z; Bs[lk + 7][lrow] = b1.w;
        __syncthreads();
#pragma unroll
        for (int k = 0; k < GBK; ++k) {
            const float4 xa0 = *(const float4*)&As[k][ty * 8];
            const float4 xa1 = *(const float4*)&As[k][ty * 8 + 4];
            const float4 wb0 = *(const float4*)&Bs[k][tx * 8];
            const float4 wb1 = *(const float4*)&Bs[k][tx * 8 + 4];
            const float xa[8] = {xa0.x, xa0.y, xa0.z, xa0.w, xa1.x, xa1.y, xa1.z, xa1.w};
            const float wv[8] = {wb0.x, wb0.y, wb0.z, wb0.w, wb1.x, wb1.y, wb1.z, wb1.w};
#pragma unroll
            for (int i = 0; i < 8; ++i)
#pragma unroll
                for (int j = 0; j < 8; ++j)
                    acc[i][j] = fmaf(xa[i], wv[j], acc[i][j]);
        }
    }

    const int orow = m0 + ty * 8;
    const int ocol = n0 + tx * 8;
#pragma unroll
    for (int i = 0; i < 8; ++i) {
        float4 o0 = make_float4(acc[i][0], acc[i][1], acc[i][2], acc[i][3]);
        float4 o1 = make_float4(acc[i][4], acc[i][5], acc[i][6], acc[i][7]);
        *(float4*)&C[(size_t)(orow + i) * D_HH + ocol]     = o0;
        *(float4*)&C[(size_t)(orow + i) * D_HH + ocol + 4] = o1;
    }
}

extern "C" void kernel_launch(void* const* d_in, const int* in_sizes, int n_in,
                              void* d_out, int out_size, void* d_ws, size_t ws_size,
                              hipStream_t stream)
{
    const float* x  = (const float*)d_in[0];   // (T, D_HH)
    const float* Wx = (const float*)d_in[1];   // (L, D_HH, D_HH)
    const float* Wh = (const float*)d_in[2];   // (L, D_HH, D_HH)
    const float* b  = (const float*)d_in[3];   // (L, D_HH)
    const float* V1 = (const float*)d_in[4];   // (L, D_HH, DR1)
    const float* U1 = (const float*)d_in[5];   // (L, DR1, D_HH)
    const float* V2 = (const float*)d_in[6];   // (L, D_HH, DR2)
    const float* U2 = (const float*)d_in[7];   // (L, DR2, D_HH)
    float* out = (float*)d_out;                // (T, D_HH)

    char* ws = (char*)d_ws;
    float* pre = (float*)ws;                                   // T*D_HH f32 (32 MB)
    const size_t preB = (size_t)TSTEPS * D_HH * sizeof(float);
    unsigned long long* hstate = (unsigned long long*)(ws + preB);     // 1024 * 8B
    unsigned long long* rstate = hstate + D_HH;                        // 768  * 8B
    const size_t stateB = (size_t)(D_HH + DR1 + DR2) * sizeof(unsigned long long);

    const dim3 ggrid(TSTEPS / GBM, D_HH / GBN);

    for (int l = 0; l < LAYERS; ++l) {
        const float* xin = (l == 0) ? x : out;   // layer 2 input = layer 1 output
        hipMemsetAsync(hstate, 0, stateB, stream);
        gemm_nt_kernel<<<ggrid, 256, 0, stream>>>(
            xin, Wx + (size_t)l * D_HH * D_HH, pre);
        crsd_scan<<<dim3(NB), dim3(BS), 0, stream>>>(
            pre,
            Wh + (size_t)l * D_HH * D_HH,
            V1 + (size_t)l * D_HH * DR1,
            V2 + (size_t)l * D_HH * DR2,
            U1 + (size_t)l * DR1 * D_HH,
            U2 + (size_t)l * DR2 * D_HH,
            b  + (size_t)l * D_HH,
            out, hstate, rstate);
    }
}

// Round 4
// 29486.447 us; speedup vs baseline: 4.4228x; 2.3710x over previous
//
#include <hip/hip_runtime.h>

// ---------------- problem constants ----------------
#define D_HH   1024
#define DR1    512
#define DR2    256
#define RTOT   (DR1 + DR2)
#define TSTEPS 8192
#define LAYERS 2

// ---------------- fused scan config ----------------
#define NB    64          // WGs per layer (2 layers -> 128 WGs total)
#define BS    512         // threads per WG (8 waves)
#define HA    (D_HH / NB) // 16 h-rows owned per WG
#define QA    (RTOT / NB) // 12 reservoir rows per WG
#define NROWB (HA + QA)   // 28 phase-B rows per WG
#define RING  64          // h1 ring depth (steps); tags self-validate slots
#define RMASK (RING - 1)

__device__ __forceinline__ float dot4f(float4 a, float4 b) {
    return fmaf(a.x, b.x, fmaf(a.y, b.y, fmaf(a.z, b.z, a.w * b.w)));
}

__device__ __forceinline__ unsigned long long ldtag(const unsigned long long* p) {
    return __hip_atomic_load(p, __ATOMIC_RELAXED, __HIP_MEMORY_SCOPE_AGENT);
}
__device__ __forceinline__ void sttag(unsigned long long* p, int tag, float v) {
    unsigned long long pv =
        ((unsigned long long)(unsigned)tag << 32) | __float_as_uint(v);
    __hip_atomic_store(p, pv, __ATOMIC_RELAXED, __HIP_MEMORY_SCOPE_AGENT);
}

// Fused dual-layer persistent recurrent scan.
//   blocks 0..63   = layer 0 (reads x from global, publishes h1 into tagged ring)
//   blocks 64..127 = layer 1 (reads x = h1 from ring, writes final out)
// Exchange = 8B tagged values (tag<<32)|f32bits at agent scope:
//   h[i] of step t  -> tag t+1  (layer0: ring slot t&63; layer1: h2state)
//   r[j] of step t  -> tag t+1  (per-layer rstate; memset0 => r_{-1}=0, tag 0)
// zw for step t+1 (= b + Wx x_{t+1} + Wh h_t) is computed in phase B of step t;
// Wx is applied IN-SCAN (no pre-GEMM).
__global__ __launch_bounds__(BS, 2) void crsd_fused(
    const float* __restrict__ x,    // (T, D_HH) layer-0 input
    const float* __restrict__ Wx,   // (L, D_HH, D_HH)
    const float* __restrict__ Wh,   // (L, D_HH, D_HH)
    const float* __restrict__ bias, // (L, D_HH)
    const float* __restrict__ V1,   // (L, D_HH, DR1)
    const float* __restrict__ U1,   // (L, DR1, D_HH)
    const float* __restrict__ V2,   // (L, D_HH, DR2)
    const float* __restrict__ U2,   // (L, DR2, D_HH)
    float* __restrict__ out,        // (T, D_HH) = layer-1 h sequence
    unsigned long long* ring,       // RING*D_HH tagged h1 (memset 0)
    unsigned long long* h2state,    // D_HH tagged h2 (memset 0)
    unsigned long long* r1state,    // RTOT tagged r (layer 0, memset 0)
    unsigned long long* r2state)    // RTOT tagged r (layer 1, memset 0)
{
    const int gid   = blockIdx.x;
    const int layer = gid >> 6;
    const int g     = gid & (NB - 1);
    const int tid   = threadIdx.x;

    const float* wxp = Wx + (size_t)layer * D_HH * D_HH;
    const float* whp = Wh + (size_t)layer * D_HH * D_HH;
    const float* v1p = V1 + (size_t)layer * D_HH * DR1;
    const float* v2p = V2 + (size_t)layer * D_HH * DR2;
    const float* u1p = U1 + (size_t)layer * DR1 * D_HH;
    const float* u2p = U2 + (size_t)layer * DR2 * D_HH;
    const float* bp  = bias + (size_t)layer * D_HH;
    unsigned long long* rstate = layer ? r2state : r1state;

    __shared__ __align__(16) float r_s[RTOT];
    __shared__ __align__(16) float h_s[D_HH];
    __shared__ __align__(16) float x_s[D_HH];
    __shared__ float zw[HA];

    // ---- phase A role: row rA (32 lanes/row); V rows in VGPRs (permuted) ----
    const int rA = tid >> 5;
    const int p  = tid & 31;
    const int iA = g * HA + rA;
    float4 wa[6];
    {
        const float4* v1r = (const float4*)(v1p + (size_t)iA * DR1);
#pragma unroll
        for (int k = 0; k < 4; ++k) wa[k] = v1r[p + 32 * k];
        const float4* v2r = (const float4*)(v2p + (size_t)iA * DR2);
#pragma unroll
        for (int k = 0; k < 2; ++k) wa[4 + k] = v2r[p + 32 * k];
    }

    // ---- phase B role: row rB (16 lanes/row); Wh/U + Wx rows in VGPRs ----
    const int rB = tid >> 4;
    const int q  = tid & 15;
    const bool isZ = (rB < HA);
    const bool isQ = (rB >= HA) && (rB < NROWB);
    int jG = 0;
    float bi = 0.f;
    const float* brow = whp;           // dummy-safe
    const float* xrow = whp;           // dummy-safe
    if (isZ) {
        brow = whp + (size_t)(g * HA + rB) * D_HH;
        xrow = wxp + (size_t)(g * HA + rB) * D_HH;
        bi   = bp[g * HA + rB];
    } else if (isQ) {
        jG = g * QA + (rB - HA);
        brow = (jG < DR1) ? (u1p + (size_t)jG * D_HH)
                          : (u2p + (size_t)(jG - DR1) * D_HH);
    }
    float4 wb[16], wxr[16];
    {
        const float4* br = (const float4*)brow;
        const float4* xr = (const float4*)xrow;
#pragma unroll
        for (int k = 0; k < 16; ++k) { wb[k] = br[q + 16 * k]; wxr[k] = xr[q + 16 * k]; }
    }

    float rloc = 0.f;        // owned reservoir element (isQ && q==0)
    int   l2c  = 0;          // cached layer-1 progress (layer-0 thread 0 only)

    // ---------------- prologue: stage x_0, compute zw for t=0 ----------------
    if (layer == 0) {
        float2 xv = *(const float2*)&x[2 * tid];
        x_s[2 * tid] = xv.x; x_s[2 * tid + 1] = xv.y;
    } else {
        bool d0 = false, d1 = false;
        while (!(d0 && d1)) {
            unsigned long long v0 = 0, v1 = 0;
            if (!d0) v0 = ldtag(&ring[tid]);
            if (!d1) v1 = ldtag(&ring[tid + BS]);
            if (!d0 && (int)(v0 >> 32) >= 1) { x_s[tid] = __uint_as_float((unsigned)v0); d0 = true; }
            if (!d1 && (int)(v1 >> 32) >= 1) { x_s[tid + BS] = __uint_as_float((unsigned)v1); d1 = true; }
            if (!(d0 && d1)) __builtin_amdgcn_s_sleep(1);
        }
    }
    __syncthreads();
    if (isZ) {
        const float4* x4 = (const float4*)x_s;
        float acc = 0.f;
#pragma unroll
        for (int k = 0; k < 16; ++k) acc += dot4f(wxr[k], x4[q + 16 * k]);
#pragma unroll
        for (int m = 8; m >= 1; m >>= 1) acc += __shfl_xor(acc, m);
        if (q == 0) zw[rB] = bi + acc;   // h_{-1}=0: no Wh term
    }
    // (t=0 r-poll barrier orders zw writes vs phase-A reads)

    for (int t = 0; t < TSTEPS; ++t) {
        // ---- layer-0 ring back-pressure (lazy, thread 0; margin 2 slots) ----
        if (layer == 0 && tid == 0 && t - 60 > l2c) {
            unsigned long long v;
            do { v = ldtag(&h2state[g * HA]); } while ((int)(v >> 32) < t - 60);
            l2c = (int)(v >> 32);
        }

        // ---- stage r_{t-1}: dual-outstanding poll, tags >= t ----
        {
            const bool has1 = (tid < (RTOT - BS));   // tid < 256
            bool d0 = false, d1 = !has1;
            while (!(d0 && d1)) {
                unsigned long long v0 = 0, v1 = 0;
                if (!d0) v0 = ldtag(&rstate[tid]);
                if (!d1) v1 = ldtag(&rstate[tid + BS]);
                if (!d0 && (int)(v0 >> 32) >= t) { r_s[tid] = __uint_as_float((unsigned)v0); d0 = true; }
                if (!d1 && (int)(v1 >> 32) >= t) { r_s[tid + BS] = __uint_as_float((unsigned)v1); d1 = true; }
                if (!(d0 && d1)) __builtin_amdgcn_s_sleep(1);
            }
        }
        __syncthreads();

        // ---- phase A: h_t = tanh(zw + V1 r1 + V2 r2) ----
        unsigned long long* hdst = layer ? h2state
                                         : (ring + (size_t)(t & RMASK) * D_HH);
        {
            const float4* r1v = (const float4*)r_s;
            const float4* r2v = (const float4*)(r_s + DR1);
            float acc = dot4f(wa[0], r1v[p]);
            acc += dot4f(wa[1], r1v[p + 32]);
            acc += dot4f(wa[2], r1v[p + 64]);
            acc += dot4f(wa[3], r1v[p + 96]);
            acc += dot4f(wa[4], r2v[p]);
            acc += dot4f(wa[5], r2v[p + 32]);
#pragma unroll
            for (int m = 16; m >= 1; m >>= 1) acc += __shfl_xor(acc, m);
            if (p == 0) {
                float hv = tanhf(zw[rA] + acc);
                sttag(&hdst[iA], t + 1, hv);     // visibility first
                h_s[iA] = hv;                    // own entries: self-staged
                if (layer) out[(size_t)t * D_HH + iA] = hv;
            }
        }

        // layer-0: prefetch x_{t+1} (off critical path; clamped at the end)
        float2 xv;
        if (layer == 0) {
            const int ti = (t + 1 < TSTEPS) ? t + 1 : TSTEPS - 1;
            xv = *(const float2*)&x[(size_t)ti * D_HH + 2 * tid];
            x_s[2 * tid] = xv.x; x_s[2 * tid + 1] = xv.y;
        }

        // ---- stage h_t (skip own 16 entries) and, for layer 1, x_{t+1} ----
        {
            const unsigned long long* hsrc = hdst;
            const unsigned long long* xsrc =
                ring + (size_t)((t + 1) & RMASK) * D_HH;
            const bool needx = (layer == 1) && (t + 1 < TSTEPS);
            bool dh0 = ((tid >> 4) == g);
            bool dh1 = (((tid + BS) >> 4) == g);
            bool dx0 = !needx, dx1 = !needx;
            while (!(dh0 && dh1 && dx0 && dx1)) {
                unsigned long long v0 = 0, v1 = 0, w0 = 0, w1 = 0;
                if (!dh0) v0 = ldtag(&hsrc[tid]);
                if (!dh1) v1 = ldtag(&hsrc[tid + BS]);
                if (!dx0) w0 = ldtag(&xsrc[tid]);
                if (!dx1) w1 = ldtag(&xsrc[tid + BS]);
                if (!dh0 && (int)(v0 >> 32) >= t + 1) { h_s[tid] = __uint_as_float((unsigned)v0); dh0 = true; }
                if (!dh1 && (int)(v1 >> 32) >= t + 1) { h_s[tid + BS] = __uint_as_float((unsigned)v1); dh1 = true; }
                if (!dx0 && (int)(w0 >> 32) >= t + 2) { x_s[tid] = __uint_as_float((unsigned)w0); dx0 = true; }
                if (!dx1 && (int)(w1 >> 32) >= t + 2) { x_s[tid + BS] = __uint_as_float((unsigned)w1); dx1 = true; }
                if (!(dh0 && dh1 && dx0 && dx1)) __builtin_amdgcn_s_sleep(1);
            }
        }
        __syncthreads();

        // ---- phase B: Q rows -> r_t; Z rows -> zw_{t+1} = b + Wx x_{t+1} + Wh h_t
        if (rB < NROWB) {
            const float4* h4 = (const float4*)h_s;
            float acc = 0.f;
#pragma unroll
            for (int k = 0; k < 16; ++k) acc += dot4f(wb[k], h4[q + 16 * k]);
            if (isZ) {
                const float4* x4 = (const float4*)x_s;
#pragma unroll
                for (int k = 0; k < 16; ++k) acc += dot4f(wxr[k], x4[q + 16 * k]);
            }
#pragma unroll
            for (int m = 8; m >= 1; m >>= 1) acc += __shfl_xor(acc, m);
            if (q == 0) {
                if (isZ) {
                    zw[rB] = bi + acc;
                } else {
                    rloc = 0.9f * rloc + 0.1f * tanhf(acc);
                    sttag(&rstate[jG], t + 1, rloc);
                }
            }
        }
    }
}

extern "C" void kernel_launch(void* const* d_in, const int* in_sizes, int n_in,
                              void* d_out, int out_size, void* d_ws, size_t ws_size,
                              hipStream_t stream)
{
    const float* x  = (const float*)d_in[0];   // (T, D_HH)
    const float* Wx = (const float*)d_in[1];   // (L, D_HH, D_HH)
    const float* Wh = (const float*)d_in[2];   // (L, D_HH, D_HH)
    const float* b  = (const float*)d_in[3];   // (L, D_HH)
    const float* V1 = (const float*)d_in[4];   // (L, D_HH, DR1)
    const float* U1 = (const float*)d_in[5];   // (L, DR1, D_HH)
    const float* V2 = (const float*)d_in[6];   // (L, D_HH, DR2)
    const float* U2 = (const float*)d_in[7];   // (L, RES2, D_HH)
    float* out = (float*)d_out;                // (T, D_HH)

    unsigned long long* ring    = (unsigned long long*)d_ws;       // RING*D_HH
    unsigned long long* h2state = ring + (size_t)RING * D_HH;      // D_HH
    unsigned long long* r1state = h2state + D_HH;                  // RTOT
    unsigned long long* r2state = r1state + RTOT;                  // RTOT
    const size_t stateB =
        ((size_t)RING * D_HH + D_HH + 2 * RTOT) * sizeof(unsigned long long);

    hipMemsetAsync(d_ws, 0, stateB, stream);
    crsd_fused<<<dim3(2 * NB), dim3(BS), 0, stream>>>(
        x, Wx, Wh, b, V1, U1, V2, U2, out, ring, h2state, r1state, r2state);
}